// Round 14
// baseline (1027.645 us; speedup 1.0000x reference)
//
#include <hip/hip_runtime.h>
#include <hip/hip_fp16.h>

#define NN 1048576   // nodes
#define NE 8388608   // edges
#define NG 16384     // graphs
#define NBUCK 256    // dst buckets (4096 nodes each)
#define BSH 12       // bucket shift
#define EPB (NE / 256)   // edges per partition block = 32768

typedef _Float16 half8 __attribute__((ext_vector_type(8)));
typedef float f32x16 __attribute__((ext_vector_type(16)));

// ---------------- node embedding: hA = f16(x @ W_emb^T + b_emb) ----------------
__global__ __launch_bounds__(256) void k_embed(const float* __restrict__ x,
    const float* __restrict__ W, const float* __restrict__ b, __half* __restrict__ h) {
  __shared__ float sW[160];
  __shared__ float sb[32];
  int t = threadIdx.x;
  if (t < 160) sW[t] = W[t];
  if (t < 32) sb[t] = b[t];
  __syncthreads();
  int idx = blockIdx.x * 256 + t;      // (node, channel)
  int c = idx & 31, n = idx >> 5;
  const float* xr = x + n * 5;
  float acc = sb[c];
#pragma unroll
  for (int k = 0; k < 5; ++k) acc = fmaf(xr[k], sW[c * 5 + k], acc);
  h[idx] = __float2half(acc);
}

// ---------------- radix pass 1: per-(block,bucket) histogram ----------------
__global__ __launch_bounds__(256) void k_pcnt(const int* __restrict__ dst, int* __restrict__ hist) {
  __shared__ int lh[NBUCK];
  int t = threadIdx.x;
  lh[t] = 0;
  __syncthreads();
  int base = blockIdx.x * EPB;
  for (int e = base + t; e < base + EPB; e += 256)
    atomicAdd(&lh[dst[e] >> BSH], 1);
  __syncthreads();
  hist[t * 256 + blockIdx.x] = lh[t];
}

// ---------------- radix pass 2a: per-bucket row scan + totals ----------------
__global__ __launch_bounds__(256) void k_scanA(int* __restrict__ hist, int* __restrict__ tot) {
  __shared__ int s2[256];
  int b = blockIdx.x, t = threadIdx.x;
  int v = hist[b * 256 + t];
  s2[t] = v; __syncthreads();
  for (int st = 1; st < 256; st <<= 1) {
    int a = (t >= st) ? s2[t - st] : 0; __syncthreads(); s2[t] += a; __syncthreads();
  }
  hist[b * 256 + t] = s2[t] - v;
  if (t == 255) tot[b] = s2[255];
}

// ---------------- radix pass 2b: scan bucket totals -> gbase ----------------
__global__ __launch_bounds__(256) void k_scanB(const int* __restrict__ tot, int* __restrict__ gbase) {
  __shared__ int s2[256];
  int t = threadIdx.x;
  int c = tot[t];
  s2[t] = c; __syncthreads();
  for (int st = 1; st < 256; st <<= 1) {
    int a = (t >= st) ? s2[t - st] : 0; __syncthreads(); s2[t] += a; __syncthreads();
  }
  gbase[t] = s2[t] - c;
  if (t == 255) gbase[256] = s2[255];
}

// ---------------- radix pass 3: partition; record = ((src<<12)|dlocal, w) ----------------
__global__ __launch_bounds__(256) void k_part(const int* __restrict__ ei, const float* __restrict__ ew,
                                              const int* __restrict__ hist, const int* __restrict__ gbase,
                                              uint2* __restrict__ bsw) {
  __shared__ int cur[NBUCK];
  int t = threadIdx.x, blk = blockIdx.x;
  cur[t] = gbase[t] + hist[t * 256 + blk];
  __syncthreads();
  int base = blk * EPB;
  for (int e = base + t; e < base + EPB; e += 256) {
    int src = ei[e];
    int d   = ei[NE + e];
    unsigned wb = __float_as_uint(ew[e]);
    int b = d >> BSH;
    int pos = atomicAdd(&cur[b], 1);
    bsw[pos] = make_uint2(((unsigned)src << 12) | (unsigned)(d & 4095), wb);
  }
}

// ------- per-bucket CSR finalize (packed records; no bdd array) -------
__global__ __launch_bounds__(256) void k_fillD(const int* __restrict__ gbase, const uint2* __restrict__ bsw,
                                               int* __restrict__ rowptr, uint2* __restrict__ colw) {
  __shared__ int loc[4096];
  __shared__ int s2[256];
  int t = threadIdx.x, b = blockIdx.x;
  int beg = gbase[b], end = gbase[b + 1], gb = beg;
  int node_base = b << BSH;
#pragma unroll
  for (int j = 0; j < 16; ++j) loc[t * 16 + j] = 0;
  __syncthreads();
  for (int i = beg + t; i < end; i += 256) atomicAdd(&loc[bsw[i].x & 4095], 1);
  __syncthreads();
  int v[16]; int tsum = 0;
#pragma unroll
  for (int j = 0; j < 16; ++j) { v[j] = loc[t * 16 + j]; tsum += v[j]; }
  s2[t] = tsum; __syncthreads();
  for (int st = 1; st < 256; st <<= 1) {
    int a = (t >= st) ? s2[t - st] : 0; __syncthreads(); s2[t] += a; __syncthreads();
  }
  int run = s2[t] - tsum;
#pragma unroll
  for (int j = 0; j < 16; ++j) {
    loc[t * 16 + j] = run;
    rowptr[node_base + t * 16 + j] = gb + run;
    run += v[j];
  }
  if (b == NBUCK - 1 && t == 255) rowptr[NN] = NE;
  __syncthreads();
  for (int i = beg + t; i < end; i += 256) {
    uint2 r = bsw[i];
    int p = atomicAdd(&loc[r.x & 4095], 1);
    colw[gb + p] = make_uint2(r.x >> 12, r.y);
  }
}

// ---------------- graph rowptr from sorted batch ----------------
__global__ __launch_bounds__(256) void k_gbound(const int* __restrict__ batch, int* __restrict__ gptr) {
  int n = blockIdx.x * 256 + threadIdx.x;
  int b = batch[n];
  int prev = (n == 0) ? -1 : batch[n - 1];
  for (int g = prev + 1; g <= b; ++g) gptr[g] = n;
  if (n == NN - 1) {
    for (int g = b + 1; g <= NG; ++g) gptr[g] = NN;
  }
}

// ------ fused [BN+ReLU of input] + pull-aggregate + MFMA dual-linear + BN stats ------
// scalar 8-deep gather; rowptr hoisted per-tile; colw prefetched one round ahead.
// __launch_bounds__(256,8) pins VGPR<=64 (occupancy cliff at 64 — R11 vs R13 evidence).
template <int FUSE_BN>
__global__ __launch_bounds__(256, 8) void k_agglin(
    const int* __restrict__ rowptr, const uint2* __restrict__ colw,
    const __half* __restrict__ hIn, const float* __restrict__ bnss,
    const float* __restrict__ Wrel, const float* __restrict__ brel,
    const float* __restrict__ Wroot, __half* __restrict__ hPre,
    double* __restrict__ stats) {
  __shared__ __half sA[4][1024];      // per-wave 32x32 f16 agg tile (XOR-swizzled)
  __shared__ uint2 sE[256];           // per-group 32-record edge staging
  __shared__ float sBn[64];
  __shared__ double rS[256], rQ[256];
  int t = threadIdx.x;
  int wv = t >> 6, lane = t & 63;
  int c = lane & 31, hi = lane >> 5, grp = t >> 5;
  char* myA = (char*)sA[wv];

  if (FUSE_BN && t < 64) sBn[t] = bnss[t];
  __syncthreads();

  float bs0 = 0.f, bs1 = 0.f;
  if constexpr (FUSE_BN) { bs0 = bnss[c]; bs1 = bnss[32 + c]; }

  // B fragments in registers: B[k][c], k = 16m + hi*8 + j
  half8 bfr[4];
#pragma unroll
  for (int m = 0; m < 4; ++m)
#pragma unroll
    for (int j = 0; j < 8; ++j) {
      int k = 16 * m + hi * 8 + j;
      float w = (k < 32) ? Wrel[c * 32 + k] : Wroot[c * 32 + (k - 32)];
      bfr[m][j] = (_Float16)w;
    }
  float bias = brel[c];
  float aS = 0.f, aQ = 0.f;           // f32 per-thread partials (<=2048 terms); double at reduce

  for (int tile = blockIdx.x * 4 + wv; tile < NN / 32; tile += gridDim.x * 4) {
    int nbase = tile * 32;
    // hoist this tile's 33 rowptr entries into lane-indexed register
    int rp = 0;
    if (lane < 33) rp = rowptr[nbase + lane];
    int r0 = __shfl(rp, hi, 64);
    int r1 = __shfl(rp, hi + 1, 64);
    uint2 cw = make_uint2(0u, 0u);
    { int m_ = r1 - r0; if (m_ > 32) m_ = 32; if (c < m_) cw = colw[r0 + c]; }

    for (int r = 0; r < 16; ++r) {
      sE[t] = cw;                                  // stage current round (same-wave LDS)
      int sr0 = r0, sr1 = r1;
      if (r < 15) {                                // prefetch next round's first segment
        r0 = __shfl(rp, 2 * (r + 1) + hi, 64);
        r1 = __shfl(rp, 2 * (r + 1) + hi + 1, 64);
        cw = make_uint2(0u, 0u);
        int m_ = r1 - r0; if (m_ > 32) m_ = 32;
        if (c < m_) cw = colw[r0 + c];
      }
      float acc = 0.f;
      // first (prefetched) segment
      {
        int m_ = sr1 - sr0; if (m_ > 32) m_ = 32;
        int mm = (m_ + 7) & ~7;
        for (int i = 0; i < mm; i += 8) {
          const uint4* eb4 = (const uint4*)&sE[grp * 32 + i];
          uint4 q0 = eb4[0], q1 = eb4[1], q2 = eb4[2], q3 = eb4[3];
          float h0 = __half2float(hIn[(size_t)q0.x * 32 + c]);
          float h1 = __half2float(hIn[(size_t)q0.z * 32 + c]);
          float h2 = __half2float(hIn[(size_t)q1.x * 32 + c]);
          float h3 = __half2float(hIn[(size_t)q1.z * 32 + c]);
          float h4 = __half2float(hIn[(size_t)q2.x * 32 + c]);
          float h5 = __half2float(hIn[(size_t)q2.z * 32 + c]);
          float h6 = __half2float(hIn[(size_t)q3.x * 32 + c]);
          float h7 = __half2float(hIn[(size_t)q3.z * 32 + c]);
          if constexpr (FUSE_BN) {
            h0 = fmaxf(fmaf(h0, bs0, bs1), 0.f); h1 = fmaxf(fmaf(h1, bs0, bs1), 0.f);
            h2 = fmaxf(fmaf(h2, bs0, bs1), 0.f); h3 = fmaxf(fmaf(h3, bs0, bs1), 0.f);
            h4 = fmaxf(fmaf(h4, bs0, bs1), 0.f); h5 = fmaxf(fmaf(h5, bs0, bs1), 0.f);
            h6 = fmaxf(fmaf(h6, bs0, bs1), 0.f); h7 = fmaxf(fmaf(h7, bs0, bs1), 0.f);
          }
          acc = fmaf(__uint_as_float(q0.y), h0, acc);
          acc = fmaf(__uint_as_float(q0.w), h1, acc);
          acc = fmaf(__uint_as_float(q1.y), h2, acc);
          acc = fmaf(__uint_as_float(q1.w), h3, acc);
          acc = fmaf(__uint_as_float(q2.y), h4, acc);
          acc = fmaf(__uint_as_float(q2.w), h5, acc);
          acc = fmaf(__uint_as_float(q3.y), h6, acc);
          acc = fmaf(__uint_as_float(q3.w), h7, acc);
        }
      }
      // rare extra segments (deg > 32), inline path
      for (int j = sr0 + 32; j < sr1; j += 32) {
        int m_ = sr1 - j; if (m_ > 32) m_ = 32;
        uint2 cw2 = make_uint2(0u, 0u);
        if (c < m_) cw2 = colw[j + c];
        sE[t] = cw2;
        int mm = (m_ + 7) & ~7;
        for (int i = 0; i < mm; i += 8) {
          const uint4* eb4 = (const uint4*)&sE[grp * 32 + i];
          uint4 q0 = eb4[0], q1 = eb4[1], q2 = eb4[2], q3 = eb4[3];
          float h0 = __half2float(hIn[(size_t)q0.x * 32 + c]);
          float h1 = __half2float(hIn[(size_t)q0.z * 32 + c]);
          float h2 = __half2float(hIn[(size_t)q1.x * 32 + c]);
          float h3 = __half2float(hIn[(size_t)q1.z * 32 + c]);
          float h4 = __half2float(hIn[(size_t)q2.x * 32 + c]);
          float h5 = __half2float(hIn[(size_t)q2.z * 32 + c]);
          float h6 = __half2float(hIn[(size_t)q3.x * 32 + c]);
          float h7 = __half2float(hIn[(size_t)q3.z * 32 + c]);
          if constexpr (FUSE_BN) {
            h0 = fmaxf(fmaf(h0, bs0, bs1), 0.f); h1 = fmaxf(fmaf(h1, bs0, bs1), 0.f);
            h2 = fmaxf(fmaf(h2, bs0, bs1), 0.f); h3 = fmaxf(fmaf(h3, bs0, bs1), 0.f);
            h4 = fmaxf(fmaf(h4, bs0, bs1), 0.f); h5 = fmaxf(fmaf(h5, bs0, bs1), 0.f);
            h6 = fmaxf(fmaf(h6, bs0, bs1), 0.f); h7 = fmaxf(fmaf(h7, bs0, bs1), 0.f);
          }
          acc = fmaf(__uint_as_float(q0.y), h0, acc);
          acc = fmaf(__uint_as_float(q0.w), h1, acc);
          acc = fmaf(__uint_as_float(q1.y), h2, acc);
          acc = fmaf(__uint_as_float(q1.w), h3, acc);
          acc = fmaf(__uint_as_float(q2.y), h4, acc);
          acc = fmaf(__uint_as_float(q2.w), h5, acc);
          acc = fmaf(__uint_as_float(q3.y), h6, acc);
          acc = fmaf(__uint_as_float(q3.w), h7, acc);
        }
      }
      int node = 2 * r + hi;
      int bw = (node * 64 + c * 2) ^ ((node & 7) << 4);
      *(__half*)(myA + bw) = __float2half(acc);
    }
    // ---- MFMA epilogue (wave-private; same-wave LDS ordering) ----
    f32x16 d;
#pragma unroll
    for (int r = 0; r < 16; ++r) d[r] = bias;
#pragma unroll
    for (int m = 0; m < 4; ++m) {
      half8 a;
      if (m < 2) {
        int node = c;                               // A row = lane&31
        int br = (node * 64 + (16 * m + hi * 8) * 2) ^ ((node & 7) << 4);
        a = *(const half8*)(myA + br);
      } else {
        int chb = 16 * (m - 2) + hi * 8;            // h channel base
        a = *(const half8*)(hIn + (size_t)(nbase + c) * 32 + chb);
        if constexpr (FUSE_BN) {
#pragma unroll
          for (int j = 0; j < 8; ++j) {
            float v = (float)a[j];
            v = fmaxf(fmaf(v, sBn[chb + j], sBn[32 + chb + j]), 0.f);
            a[j] = (_Float16)v;
          }
        }
      }
      d = __builtin_amdgcn_mfma_f32_32x32x16_f16(a, bfr[m], d, 0, 0, 0);
    }
    // ---- store + BN stats; D: col=lane&31, row=(r&3)+8*(r>>2)+4*hi ----
#pragma unroll
    for (int r = 0; r < 16; ++r) {
      int node = (r & 3) + 8 * (r >> 2) + 4 * hi;
      float v = d[r];
      hPre[(size_t)(nbase + node) * 32 + c] = __float2half(v);
      aS += v; aQ += v * v;
    }
  }
  rS[t] = (double)aS; rQ[t] = (double)aQ;
  __syncthreads();
  for (int s = 128; s >= 32; s >>= 1) {
    if (t < s) { rS[t] += rS[t + s]; rQ[t] += rQ[t + s]; }
    __syncthreads();
  }
  if (t < 32) {
    atomicAdd(&stats[t], rS[t]);
    atomicAdd(&stats[32 + t], rQ[t]);
  }
}

// ---------------- finalize BN ----------------
__global__ void k_bnfin(const double* __restrict__ stats, const float* __restrict__ gamma,
                        const float* __restrict__ beta, float* __restrict__ ss) {
  int c = threadIdx.x;
  double mean = stats[c] * (1.0 / NN);
  double var = stats[32 + c] * (1.0 / NN) - mean * mean;
  float scale = gamma[c] * (float)(1.0 / sqrt(var + 1e-5));
  ss[c] = scale;
  ss[32 + c] = beta[c] - (float)mean * scale;
}

// ------- layer-2 BN apply + ReLU + segment-max pool (half2, 4 node-slots) -------
__global__ __launch_bounds__(256) void k_pool(const __half* __restrict__ hB,
    const float* __restrict__ ss, const int* __restrict__ gptr, float* __restrict__ pooled) {
  int t = threadIdx.x;
  int wv = t >> 6, lane = t & 63;
  int p = lane >> 4, cl = lane & 15;          // 4 nodes in flight, 2 ch/lane
  float s0x = ss[2 * cl], s0y = ss[2 * cl + 1];
  float s1x = ss[32 + 2 * cl], s1y = ss[32 + 2 * cl + 1];
  int g = blockIdx.x * 4 + wv;                // grid 4096 x 4 waves = NG exactly
  int a = gptr[g], b = gptr[g + 1];
  float mx = 0.f, my = 0.f;                   // post-ReLU max >= 0
  for (int n = a + p; n < b; n += 4) {
    float2 hv = __half22float2(*(const __half2*)(hB + (size_t)n * 32 + 2 * cl));
    mx = fmaxf(mx, fmaf(hv.x, s0x, s1x));
    my = fmaxf(my, fmaf(hv.y, s0y, s1y));
  }
  mx = fmaxf(mx, __shfl_xor(mx, 16, 64)); my = fmaxf(my, __shfl_xor(my, 16, 64));
  mx = fmaxf(mx, __shfl_xor(mx, 32, 64)); my = fmaxf(my, __shfl_xor(my, 32, 64));
  if (p == 0) *(float2*)&pooled[g * 32 + 2 * cl] = make_float2(mx, my);
}

// ---------------- MLP head ----------------
__global__ __launch_bounds__(256) void k_head(const float* __restrict__ pooled,
    const float* __restrict__ W1, const float* __restrict__ b1,
    const float* __restrict__ W2, const float* __restrict__ b2, float* __restrict__ out) {
  __shared__ float sW1[64 * 33], sW2[10 * 65], sb1[64], sb2[10];
  __shared__ float sHid[4][64];
  int t = threadIdx.x;
  for (int i = t; i < 2048; i += 256) sW1[(i >> 5) * 33 + (i & 31)] = W1[i];
  for (int i = t; i < 640; i += 256) sW2[(i >> 6) * 65 + (i & 63)] = W2[i];
  if (t < 64) sb1[t] = b1[t];
  if (t < 10) sb2[t] = b2[t];
  __syncthreads();
  int w = t >> 6, lane = t & 63;
  for (int g = blockIdx.x * 4 + w; g < NG; g += gridDim.x * 4) {
    float pv = (lane < 32) ? pooled[g * 32 + lane] : 0.f;
    float acc = sb1[lane];
#pragma unroll
    for (int k = 0; k < 32; ++k)
      acc = fmaf(__shfl(pv, k, 64), sW1[lane * 33 + k], acc);
    acc = fmaxf(acc, 0.f);
    sHid[w][lane] = acc;
    __syncthreads();
    if (lane < 10) {
      float o = sb2[lane];
#pragma unroll
      for (int j = 0; j < 64; ++j) o = fmaf(sHid[w][j], sW2[lane * 65 + j], o);
      out[g * 10 + lane] = o;
    }
    __syncthreads();
  }
}

extern "C" void kernel_launch(void* const* d_in, const int* in_sizes, int n_in,
                              void* d_out, int out_size, void* d_ws, size_t ws_size,
                              hipStream_t stream) {
  const float* x      = (const float*)d_in[0];
  const int*   ei     = (const int*)d_in[1];
  const float* ea     = (const float*)d_in[2];
  const int*   batch  = (const int*)d_in[3];
  const float* W_emb  = (const float*)d_in[4];
  const float* b_emb  = (const float*)d_in[5];
  const float* W_rel  = (const float*)d_in[6];
  const float* b_rel  = (const float*)d_in[7];
  const float* W_root = (const float*)d_in[8];
  const float* gamma  = (const float*)d_in[9];
  const float* beta   = (const float*)d_in[10];
  const float* W1     = (const float*)d_in[11];
  const float* b1     = (const float*)d_in[12];
  const float* W2     = (const float*)d_in[13];
  const float* b2     = (const float*)d_in[14];
  float* out = (float*)d_out;

  // ---- workspace layout (~200 MiB of 256 MiB) ----
  char* ws = (char*)d_ws;
  size_t off = 0;
  __half* hA    = (__half*)(ws + off); off += (size_t)NN * 32 * 2;          // 64 MiB
  uint2*  colw  = (uint2*)(ws + off);  off += (size_t)NE * 8;               // 64 MiB
  uint2*  bsw   = (uint2*)(ws + off);                                        // 64 MiB
  __half* hB    = (__half*)(ws + off);                                       // ALIASES bsw (dead before hB written)
  off += (size_t)NE * 8;
  int*    rowptr= (int*)(ws + off);    off += ((size_t)NN + 64) * 4;        // 4 MiB
  int*    hist  = (int*)(ws + off);    off += (size_t)NBUCK * 256 * 4;      // 256 KiB
  int*    tot   = (int*)(ws + off);    off += 1024;
  int*    gbase = (int*)(ws + off);    off += 2048;
  int*    gptr  = (int*)(ws + off);    off += ((size_t)NG + 64) * 4;
  float*  pooled= (float*)(ws + off);
  double* stats = (double*)d_out;                   // overwritten by k_head later
  float*  ss0   = (float*)((char*)d_out + 512);
  float*  ss1   = (float*)((char*)d_out + 768);

  k_embed<<<NN * 32 / 256, 256, 0, stream>>>(x, W_emb, b_emb, hA);

  // ---- radix-partition CSR build ----
  k_pcnt <<<256, 256, 0, stream>>>(ei + NE, hist);
  k_scanA<<<NBUCK, 256, 0, stream>>>(hist, tot);
  k_scanB<<<1, 256, 0, stream>>>(tot, gbase);
  k_part <<<256, 256, 0, stream>>>(ei, ea, hist, gbase, bsw);
  k_fillD<<<NBUCK, 256, 0, stream>>>(gbase, bsw, rowptr, colw);
  k_gbound<<<NN / 256, 256, 0, stream>>>(batch, gptr);

  // ---- layer 1: embed(hA) -> pre-BN hB ----
  (void)hipMemsetAsync(stats, 0, 64 * 8, stream);
  k_agglin<0><<<2048, 256, 0, stream>>>(rowptr, colw, hA, nullptr,
                                        W_rel, b_rel, W_root, hB, stats);
  k_bnfin<<<1, 32, 0, stream>>>(stats, gamma, beta, ss0);

  // ---- layer 2: BN/ReLU fused on hB input -> pre-BN hA (hA dead after L1) ----
  (void)hipMemsetAsync(stats, 0, 64 * 8, stream);
  k_agglin<1><<<2048, 256, 0, stream>>>(rowptr, colw, hB, ss0,
                                        W_rel + 1024, b_rel + 32, W_root + 1024, hA, stats);
  k_bnfin<<<1, 32, 0, stream>>>(stats, gamma + 32, beta + 32, ss1);

  k_pool<<<NG / 4, 256, 0, stream>>>(hA, ss1, gptr, pooled);
  k_head<<<1024, 256, 0, stream>>>(pooled, W1, b1, W2, b2, out);
}

// Round 15
// 974.877 us; speedup vs baseline: 1.0541x; 1.0541x over previous
//
#include <hip/hip_runtime.h>
#include <hip/hip_fp16.h>

#define NN 1048576   // nodes
#define NE 8388608   // edges
#define NG 16384     // graphs
#define NBUCK 256    // dst buckets (4096 nodes each)
#define BSH 12       // bucket shift
#define EPB (NE / 256)   // edges per partition block = 32768

typedef _Float16 half8 __attribute__((ext_vector_type(8)));
typedef float f32x16 __attribute__((ext_vector_type(16)));

// ---------------- node embedding: hA = f16(x @ W_emb^T + b_emb) ----------------
__global__ __launch_bounds__(256) void k_embed(const float* __restrict__ x,
    const float* __restrict__ W, const float* __restrict__ b, __half* __restrict__ h) {
  __shared__ float sW[160];
  __shared__ float sb[32];
  int t = threadIdx.x;
  if (t < 160) sW[t] = W[t];
  if (t < 32) sb[t] = b[t];
  __syncthreads();
  int idx = blockIdx.x * 256 + t;      // (node, channel)
  int c = idx & 31, n = idx >> 5;
  const float* xr = x + n * 5;
  float acc = sb[c];
#pragma unroll
  for (int k = 0; k < 5; ++k) acc = fmaf(xr[k], sW[c * 5 + k], acc);
  h[idx] = __float2half(acc);
}

// ---------------- radix pass 1: per-(block,bucket) histogram ----------------
__global__ __launch_bounds__(256) void k_pcnt(const int* __restrict__ dst, int* __restrict__ hist) {
  __shared__ int lh[NBUCK];
  int t = threadIdx.x;
  lh[t] = 0;
  __syncthreads();
  int base = blockIdx.x * EPB;
  for (int e = base + t; e < base + EPB; e += 256)
    atomicAdd(&lh[dst[e] >> BSH], 1);
  __syncthreads();
  hist[t * 256 + blockIdx.x] = lh[t];
}

// ---------------- radix pass 2a: per-bucket row scan + totals ----------------
__global__ __launch_bounds__(256) void k_scanA(int* __restrict__ hist, int* __restrict__ tot) {
  __shared__ int s2[256];
  int b = blockIdx.x, t = threadIdx.x;
  int v = hist[b * 256 + t];
  s2[t] = v; __syncthreads();
  for (int st = 1; st < 256; st <<= 1) {
    int a = (t >= st) ? s2[t - st] : 0; __syncthreads(); s2[t] += a; __syncthreads();
  }
  hist[b * 256 + t] = s2[t] - v;
  if (t == 255) tot[b] = s2[255];
}

// ---------------- radix pass 2b: scan bucket totals -> gbase ----------------
__global__ __launch_bounds__(256) void k_scanB(const int* __restrict__ tot, int* __restrict__ gbase) {
  __shared__ int s2[256];
  int t = threadIdx.x;
  int c = tot[t];
  s2[t] = c; __syncthreads();
  for (int st = 1; st < 256; st <<= 1) {
    int a = (t >= st) ? s2[t - st] : 0; __syncthreads(); s2[t] += a; __syncthreads();
  }
  gbase[t] = s2[t] - c;
  if (t == 255) gbase[256] = s2[255];
}

// ---------------- radix pass 3: partition; record = ((src<<12)|dlocal, w) ----------------
__global__ __launch_bounds__(256) void k_part(const int* __restrict__ ei, const float* __restrict__ ew,
                                              const int* __restrict__ hist, const int* __restrict__ gbase,
                                              uint2* __restrict__ bsw) {
  __shared__ int cur[NBUCK];
  int t = threadIdx.x, blk = blockIdx.x;
  cur[t] = gbase[t] + hist[t * 256 + blk];
  __syncthreads();
  int base = blk * EPB;
  for (int e = base + t; e < base + EPB; e += 256) {
    int src = ei[e];
    int d   = ei[NE + e];
    unsigned wb = __float_as_uint(ew[e]);
    int b = d >> BSH;
    int pos = atomicAdd(&cur[b], 1);
    bsw[pos] = make_uint2(((unsigned)src << 12) | (unsigned)(d & 4095), wb);
  }
}

// ------- per-bucket CSR finalize (packed records; no bdd array) -------
__global__ __launch_bounds__(256) void k_fillD(const int* __restrict__ gbase, const uint2* __restrict__ bsw,
                                               int* __restrict__ rowptr, uint2* __restrict__ colw) {
  __shared__ int loc[4096];
  __shared__ int s2[256];
  int t = threadIdx.x, b = blockIdx.x;
  int beg = gbase[b], end = gbase[b + 1], gb = beg;
  int node_base = b << BSH;
#pragma unroll
  for (int j = 0; j < 16; ++j) loc[t * 16 + j] = 0;
  __syncthreads();
  for (int i = beg + t; i < end; i += 256) atomicAdd(&loc[bsw[i].x & 4095], 1);
  __syncthreads();
  int v[16]; int tsum = 0;
#pragma unroll
  for (int j = 0; j < 16; ++j) { v[j] = loc[t * 16 + j]; tsum += v[j]; }
  s2[t] = tsum; __syncthreads();
  for (int st = 1; st < 256; st <<= 1) {
    int a = (t >= st) ? s2[t - st] : 0; __syncthreads(); s2[t] += a; __syncthreads();
  }
  int run = s2[t] - tsum;
#pragma unroll
  for (int j = 0; j < 16; ++j) {
    loc[t * 16 + j] = run;
    rowptr[node_base + t * 16 + j] = gb + run;
    run += v[j];
  }
  if (b == NBUCK - 1 && t == 255) rowptr[NN] = NE;
  __syncthreads();
  for (int i = beg + t; i < end; i += 256) {
    uint2 r = bsw[i];
    int p = atomicAdd(&loc[r.x & 4095], 1);
    colw[gb + p] = make_uint2(r.x >> 12, r.y);
  }
}

// ---------------- graph rowptr from sorted batch ----------------
__global__ __launch_bounds__(256) void k_gbound(const int* __restrict__ batch, int* __restrict__ gptr) {
  int n = blockIdx.x * 256 + threadIdx.x;
  int b = batch[n];
  int prev = (n == 0) ? -1 : batch[n - 1];
  for (int g = prev + 1; g <= b; ++g) gptr[g] = n;
  if (n == NN - 1) {
    for (int g = b + 1; g <= NG; ++g) gptr[g] = NN;
  }
}

// ------ fused pull-aggregate + MFMA dual-linear + BN stats (EXACT R11 body) ------
// 64-VGPR natural codegen, 8-deep scalar gather — proven 254 us/dispatch.
__global__ __launch_bounds__(256) void k_agglin(
    const int* __restrict__ rowptr, const uint2* __restrict__ colw,
    const __half* __restrict__ hIn, const float* __restrict__ Wrel,
    const float* __restrict__ brel, const float* __restrict__ Wroot,
    __half* __restrict__ hPre, double* __restrict__ stats) {
  __shared__ __half sA[4][1024];      // per-wave 32x32 f16 agg tile (XOR-swizzled)
  __shared__ uint2 sE[256];           // staged edge records
  __shared__ double rS[256], rQ[256];
  int t = threadIdx.x;
  int wv = t >> 6, lane = t & 63;
  int c = lane & 31, hi = lane >> 5, grp = t >> 5;
  char* myA = (char*)sA[wv];

  // B fragments in registers: B[k][c], k = 16m + hi*8 + j
  half8 bfr[4];
#pragma unroll
  for (int m = 0; m < 4; ++m)
#pragma unroll
    for (int j = 0; j < 8; ++j) {
      int k = 16 * m + hi * 8 + j;
      float w = (k < 32) ? Wrel[c * 32 + k] : Wroot[c * 32 + (k - 32)];
      bfr[m][j] = (_Float16)w;
    }
  float bias = brel[c];
  double aS = 0.0, aQ = 0.0;

  for (int tile = blockIdx.x * 4 + wv; tile < NN / 32; tile += gridDim.x * 4) {
    int nbase = tile * 32;
    // ---- gather: 16 rounds x 2 nodes (one per 32-lane group) ----
    for (int r = 0; r < 16; ++r) {
      int node = 2 * r + hi;
      int n = nbase + node;
      int r0 = rowptr[n], r1 = rowptr[n + 1];
      float acc = 0.f;
      for (int j = r0; j < r1; j += 32) {
        int m_ = r1 - j; if (m_ > 32) m_ = 32;
        uint2 cw = make_uint2(0u, 0u);             // pad: src=0 row, w=+0
        if (c < m_) cw = colw[j + c];
        sE[t] = cw;                                // same-wave LDS
        int mm = (m_ + 7) & ~7;
        for (int i = 0; i < mm; i += 8) {
          const uint4* eb4 = (const uint4*)&sE[grp * 32 + i];
          uint4 q0 = eb4[0], q1 = eb4[1], q2 = eb4[2], q3 = eb4[3];
          // 8 independent 2 B gathers -> 8 loads in flight
          float h0 = __half2float(hIn[(size_t)q0.x * 32 + c]);
          float h1 = __half2float(hIn[(size_t)q0.z * 32 + c]);
          float h2 = __half2float(hIn[(size_t)q1.x * 32 + c]);
          float h3 = __half2float(hIn[(size_t)q1.z * 32 + c]);
          float h4 = __half2float(hIn[(size_t)q2.x * 32 + c]);
          float h5 = __half2float(hIn[(size_t)q2.z * 32 + c]);
          float h6 = __half2float(hIn[(size_t)q3.x * 32 + c]);
          float h7 = __half2float(hIn[(size_t)q3.z * 32 + c]);
          acc = fmaf(__uint_as_float(q0.y), h0, acc);
          acc = fmaf(__uint_as_float(q0.w), h1, acc);
          acc = fmaf(__uint_as_float(q1.y), h2, acc);
          acc = fmaf(__uint_as_float(q1.w), h3, acc);
          acc = fmaf(__uint_as_float(q2.y), h4, acc);
          acc = fmaf(__uint_as_float(q2.w), h5, acc);
          acc = fmaf(__uint_as_float(q3.y), h6, acc);
          acc = fmaf(__uint_as_float(q3.w), h7, acc);
        }
      }
      // write acc to swizzled f16 tile: logical (node, k=c)
      int bw = (node * 64 + c * 2) ^ ((node & 7) << 4);
      *(__half*)(myA + bw) = __float2half(acc);
    }
    // ---- MFMA epilogue (wave-private; same-wave LDS ordering) ----
    f32x16 d;
#pragma unroll
    for (int r = 0; r < 16; ++r) d[r] = bias;
#pragma unroll
    for (int m = 0; m < 4; ++m) {
      half8 a;
      if (m < 2) {
        int node = c;                               // A row = lane&31
        int br = (node * 64 + (16 * m + hi * 8) * 2) ^ ((node & 7) << 4);
        a = *(const half8*)(myA + br);
      } else {
        int chb = 16 * (m - 2) + hi * 8;            // h channel base
        a = *(const half8*)(hIn + (size_t)(nbase + c) * 32 + chb);
      }
      d = __builtin_amdgcn_mfma_f32_32x32x16_f16(a, bfr[m], d, 0, 0, 0);
    }
    // ---- store + BN stats; D: col=lane&31, row=(r&3)+8*(r>>2)+4*hi ----
#pragma unroll
    for (int r = 0; r < 16; ++r) {
      int node = (r & 3) + 8 * (r >> 2) + 4 * hi;
      float v = d[r];
      hPre[(size_t)(nbase + node) * 32 + c] = __float2half(v);
      aS += v; aQ += (double)v * v;
    }
  }
  rS[t] = aS; rQ[t] = aQ;
  __syncthreads();
  for (int s = 128; s >= 32; s >>= 1) {
    if (t < s) { rS[t] += rS[t + s]; rQ[t] += rQ[t + s]; }
    __syncthreads();
  }
  if (t < 32) {
    atomicAdd(&stats[t], rS[t]);
    atomicAdd(&stats[32 + t], rQ[t]);
  }
}

// ---------------- finalize BN ----------------
__global__ void k_bnfin(const double* __restrict__ stats, const float* __restrict__ gamma,
                        const float* __restrict__ beta, float* __restrict__ ss) {
  int c = threadIdx.x;
  double mean = stats[c] * (1.0 / NN);
  double var = stats[32 + c] * (1.0 / NN) - mean * mean;
  float scale = gamma[c] * (float)(1.0 / sqrt(var + 1e-5));
  ss[c] = scale;
  ss[32 + c] = beta[c] - (float)mean * scale;
}

// ---------------- BN apply + ReLU (layer 1) ----------------
__global__ __launch_bounds__(256) void k_apply(const __half* __restrict__ in,
    const float* __restrict__ ss, __half* __restrict__ outp) {
  __shared__ float s0[32], s1[32];
  int t = threadIdx.x;
  if (t < 32) { s0[t] = ss[t]; s1[t] = ss[32 + t]; }
  __syncthreads();
  int idx = blockIdx.x * 256 + t;
  int c = idx & 31;
  float v = fmaxf(fmaf(__half2float(in[idx]), s0[c], s1[c]), 0.f);
  outp[idx] = __float2half(v);
}

// ------- layer-2 BN apply + ReLU + segment-max pool (half2, 4 node-slots) -------
__global__ __launch_bounds__(256) void k_pool(const __half* __restrict__ hB,
    const float* __restrict__ ss, const int* __restrict__ gptr, float* __restrict__ pooled) {
  int t = threadIdx.x;
  int wv = t >> 6, lane = t & 63;
  int p = lane >> 4, cl = lane & 15;          // 4 nodes in flight, 2 ch/lane
  float s0x = ss[2 * cl], s0y = ss[2 * cl + 1];
  float s1x = ss[32 + 2 * cl], s1y = ss[32 + 2 * cl + 1];
  int g = blockIdx.x * 4 + wv;                // grid 4096 x 4 waves = NG exactly
  int a = gptr[g], b = gptr[g + 1];
  float mx = 0.f, my = 0.f;                   // post-ReLU max >= 0
  for (int n = a + p; n < b; n += 4) {
    float2 hv = __half22float2(*(const __half2*)(hB + (size_t)n * 32 + 2 * cl));
    mx = fmaxf(mx, fmaf(hv.x, s0x, s1x));
    my = fmaxf(my, fmaf(hv.y, s0y, s1y));
  }
  mx = fmaxf(mx, __shfl_xor(mx, 16, 64)); my = fmaxf(my, __shfl_xor(my, 16, 64));
  mx = fmaxf(mx, __shfl_xor(mx, 32, 64)); my = fmaxf(my, __shfl_xor(my, 32, 64));
  if (p == 0) *(float2*)&pooled[g * 32 + 2 * cl] = make_float2(mx, my);
}

// ---------------- MLP head ----------------
__global__ __launch_bounds__(256) void k_head(const float* __restrict__ pooled,
    const float* __restrict__ W1, const float* __restrict__ b1,
    const float* __restrict__ W2, const float* __restrict__ b2, float* __restrict__ out) {
  __shared__ float sW1[64 * 33], sW2[10 * 65], sb1[64], sb2[10];
  __shared__ float sHid[4][64];
  int t = threadIdx.x;
  for (int i = t; i < 2048; i += 256) sW1[(i >> 5) * 33 + (i & 31)] = W1[i];
  for (int i = t; i < 640; i += 256) sW2[(i >> 6) * 65 + (i & 63)] = W2[i];
  if (t < 64) sb1[t] = b1[t];
  if (t < 10) sb2[t] = b2[t];
  __syncthreads();
  int w = t >> 6, lane = t & 63;
  for (int g = blockIdx.x * 4 + w; g < NG; g += gridDim.x * 4) {
    float pv = (lane < 32) ? pooled[g * 32 + lane] : 0.f;
    float acc = sb1[lane];
#pragma unroll
    for (int k = 0; k < 32; ++k)
      acc = fmaf(__shfl(pv, k, 64), sW1[lane * 33 + k], acc);
    acc = fmaxf(acc, 0.f);
    sHid[w][lane] = acc;
    __syncthreads();
    if (lane < 10) {
      float o = sb2[lane];
#pragma unroll
      for (int j = 0; j < 64; ++j) o = fmaf(sHid[w][j], sW2[lane * 65 + j], o);
      out[g * 10 + lane] = o;
    }
    __syncthreads();
  }
}

extern "C" void kernel_launch(void* const* d_in, const int* in_sizes, int n_in,
                              void* d_out, int out_size, void* d_ws, size_t ws_size,
                              hipStream_t stream) {
  const float* x      = (const float*)d_in[0];
  const int*   ei     = (const int*)d_in[1];
  const float* ea     = (const float*)d_in[2];
  const int*   batch  = (const int*)d_in[3];
  const float* W_emb  = (const float*)d_in[4];
  const float* b_emb  = (const float*)d_in[5];
  const float* W_rel  = (const float*)d_in[6];
  const float* b_rel  = (const float*)d_in[7];
  const float* W_root = (const float*)d_in[8];
  const float* gamma  = (const float*)d_in[9];
  const float* beta   = (const float*)d_in[10];
  const float* W1     = (const float*)d_in[11];
  const float* b1     = (const float*)d_in[12];
  const float* W2     = (const float*)d_in[13];
  const float* b2     = (const float*)d_in[14];
  float* out = (float*)d_out;

  // ---- workspace layout (~200 MiB of 256 MiB) ----
  char* ws = (char*)d_ws;
  size_t off = 0;
  __half* hA    = (__half*)(ws + off); off += (size_t)NN * 32 * 2;          // 64 MiB
  uint2*  colw  = (uint2*)(ws + off);  off += (size_t)NE * 8;               // 64 MiB
  uint2*  bsw   = (uint2*)(ws + off);                                        // 64 MiB
  __half* hB    = (__half*)(ws + off);                                       // ALIASES bsw (dead before hB written)
  off += (size_t)NE * 8;
  int*    rowptr= (int*)(ws + off);    off += ((size_t)NN + 64) * 4;        // 4 MiB
  int*    hist  = (int*)(ws + off);    off += (size_t)NBUCK * 256 * 4;      // 256 KiB
  int*    tot   = (int*)(ws + off);    off += 1024;
  int*    gbase = (int*)(ws + off);    off += 2048;
  int*    gptr  = (int*)(ws + off);    off += ((size_t)NG + 64) * 4;
  float*  pooled= (float*)(ws + off);
  double* stats = (double*)d_out;                   // overwritten by k_head later
  float*  ss0   = (float*)((char*)d_out + 512);
  float*  ss1   = (float*)((char*)d_out + 768);

  k_embed<<<NN * 32 / 256, 256, 0, stream>>>(x, W_emb, b_emb, hA);

  // ---- radix-partition CSR build ----
  k_pcnt <<<256, 256, 0, stream>>>(ei + NE, hist);
  k_scanA<<<NBUCK, 256, 0, stream>>>(hist, tot);
  k_scanB<<<1, 256, 0, stream>>>(tot, gbase);
  k_part <<<256, 256, 0, stream>>>(ei, ea, hist, gbase, bsw);
  k_fillD<<<NBUCK, 256, 0, stream>>>(gbase, bsw, rowptr, colw);
  k_gbound<<<NN / 256, 256, 0, stream>>>(batch, gptr);

  // ---- layer 1: agglin(hA -> hB), BN stats, apply BN+ReLU (hB -> hA) ----
  (void)hipMemsetAsync(stats, 0, 64 * 8, stream);
  k_agglin<<<2048, 256, 0, stream>>>(rowptr, colw, hA, W_rel, b_rel, W_root, hB, stats);
  k_bnfin<<<1, 32, 0, stream>>>(stats, gamma, beta, ss0);
  k_apply<<<NN * 32 / 256, 256, 0, stream>>>(hB, ss0, hA);

  // ---- layer 2: agglin(hA -> hB), BN stats, fused pool ----
  (void)hipMemsetAsync(stats, 0, 64 * 8, stream);
  k_agglin<<<2048, 256, 0, stream>>>(rowptr, colw, hA, W_rel + 1024, b_rel + 32,
                                     W_root + 1024, hB, stats);
  k_bnfin<<<1, 32, 0, stream>>>(stats, gamma + 32, beta + 32, ss1);

  k_pool<<<NG / 4, 256, 0, stream>>>(hB, ss1, gptr, pooled);
  k_head<<<1024, 256, 0, stream>>>(pooled, W1, b1, W2, b2, out);
}